// Round 23
// baseline (253.501 us; speedup 1.0000x reference)
//
#include <hip/hip_runtime.h>
#include <math.h>

#define BB 16
#define CC 256
#define TT 4096
#define NA 1024
#define NB 3072
#define OC 512

#define NCH 12         // j-chunks for MFMA sim kernel (256 j each = 2 tiles of 128)
#define NPART (NCH*2)  // partials: chunk x wc-half (race-free direct per-wave writes)
#define DELTA 2e-4f    // margin below which a row falls back to exact fp32 argmax

typedef float f32x4 __attribute__((ext_vector_type(4)));
typedef short bf16x8 __attribute__((ext_vector_type(8)));

// ---------------- K2: fused norm + transpose-pack (x read ONCE) ----------------
__global__ void __launch_bounds__(256, 2) k_pack(const float* __restrict__ x,
                                                 float* __restrict__ Ap, float* __restrict__ Bp,
                                                 int* __restrict__ count) {
    __shared__ float tilT[64][260];   // [token][c], pad 260 (mult of 4: aligned float4 rows)
    __shared__ float psum[64][17];    // [token][c-group]
    __shared__ float ns[64];
    int b = blockIdx.y, t0 = blockIdx.x * 64;
    int tid = threadIdx.x;
    if (tid == 0 && blockIdx.x == 0 && b == 0) *count = 0;
    int hi = tid >> 4, j4 = tid & 15;           // c-group lane, token-quad
    float ps0 = 0.f, ps1 = 0.f, ps2 = 0.f, ps3 = 0.f;
#pragma unroll
    for (int rep = 0; rep < 16; ++rep) {
        int i = rep * 16 + hi;                  // c row
        float4 v = *(const float4*)(x + ((size_t)b * CC + i) * TT + t0 + j4 * 4);
        tilT[j4 * 4 + 0][i] = v.x;
        tilT[j4 * 4 + 1][i] = v.y;
        tilT[j4 * 4 + 2][i] = v.z;
        tilT[j4 * 4 + 3][i] = v.w;
        ps0 = fmaf(v.x, v.x, ps0);
        ps1 = fmaf(v.y, v.y, ps1);
        ps2 = fmaf(v.z, v.z, ps2);
        ps3 = fmaf(v.w, v.w, ps3);
    }
    psum[j4 * 4 + 0][hi] = ps0;
    psum[j4 * 4 + 1][hi] = ps1;
    psum[j4 * 4 + 2][hi] = ps2;
    psum[j4 * 4 + 3][hi] = ps3;
    __syncthreads();
    if (tid < 64) {
        float s = 0.f;
#pragma unroll
        for (int g = 0; g < 16; ++g) s += psum[tid][g];
        ns[tid] = sqrtf(s);
    }
    __syncthreads();
#pragma unroll
    for (int rep = 0; rep < 16; ++rep) {
        int lin = rep * 256 + tid;
        int j = lin >> 6, i4 = lin & 63;        // token, c-quad
        float nsj = ns[j];
        const float* rp = &tilT[j][i4 * 4];
        float4 o;
        o.x = rp[0] / nsj;
        o.y = rp[1] / nsj;
        o.z = rp[2] / nsj;
        o.w = rp[3] / nsj;
        int t = t0 + j;
        if ((t & 3) == 0) {
            *(float4*)(Ap + ((size_t)b * NA + (t >> 2)) * CC + i4 * 4) = o;
        } else {
            int g = t >> 2, r = t & 3;
            *(float4*)(Bp + ((size_t)b * NB + 3 * g + (r - 1)) * CC + i4 * 4) = o;
        }
    }
}

// ---------------- K3: MFMA sim; 64x256 tile for 3 blocks/CU; T14 + T1 ----------------
__device__ inline void split8(float4 p0, float4 p1, bf16x8& hi, bf16x8& lo) {
    float f[8] = {p0.x, p0.y, p0.z, p0.w, p1.x, p1.y, p1.z, p1.w};
#pragma unroll
    for (int j = 0; j < 8; ++j) {
        uint u = __float_as_uint(f[j]);
        hi[j] = (short)(u >> 16);
        float hf = __uint_as_float(u & 0xffff0000u);
        lo[j] = (short)(__float_as_uint(f[j] - hf) >> 16);
    }
}

// A slice: 64 rows (2 reps); B slice: 128 rows (4 reps)
#define LOADTN(SRC_BASE, KT, RG, NREP)                                            \
    _Pragma("unroll")                                                             \
    for (int rep = 0; rep < NREP; ++rep) {                                        \
        int lin = rep * 256 + tid;                                                \
        int r = lin >> 3, g = lin & 7;                                            \
        const float* sp = (SRC_BASE) + (size_t)r * CC + (KT) * 64 + g * 8;        \
        RG[rep][0] = *(const float4*)sp;                                          \
        RG[rep][1] = *(const float4*)(sp + 4);                                    \
    }

#define WRITETN(RG, DH, DL, NREP)                                                 \
    _Pragma("unroll")                                                             \
    for (int rep = 0; rep < NREP; ++rep) {                                        \
        int lin = rep * 256 + tid;                                                \
        int r = lin >> 3, g = lin & 7;                                            \
        bf16x8 h8, l8;                                                            \
        split8(RG[rep][0], RG[rep][1], h8, l8);                                   \
        int off = r * 128 + ((g ^ (r & 7)) << 4);                                 \
        *(bf16x8*)((DH) + off) = h8;                                              \
        *(bf16x8*)((DL) + off) = l8;                                              \
    }

#define MFMA_TILE(ACC)                                                            \
    _Pragma("unroll")                                                             \
    for (int ks = 0; ks < 2; ++ks) {                                              \
        bf16x8 ahi[2], alo[2];                                                    \
        _Pragma("unroll")                                                         \
        for (int mf = 0; mf < 2; ++mf) {                                          \
            int ra = wr * 32 + mf * 16 + lr;                                      \
            int offa = ra * 128 + (((ks * 4 + lk) ^ (ra & 7)) << 4);              \
            ahi[mf] = *(const bf16x8*)(Ah + offa);                                \
            alo[mf] = *(const bf16x8*)(Al + offa);                                \
        }                                                                         \
        _Pragma("unroll")                                                         \
        for (int nf = 0; nf < 4; ++nf) {                                          \
            int rb = wc * 64 + nf * 16 + lr;                                      \
            int offb = rb * 128 + (((ks * 4 + lk) ^ (rb & 7)) << 4);              \
            bf16x8 bhi = *(const bf16x8*)(Bh + offb);                             \
            bf16x8 blo = *(const bf16x8*)(Bl + offb);                             \
            _Pragma("unroll")                                                     \
            for (int mf = 0; mf < 2; ++mf) {                                      \
                ACC[mf][nf] = __builtin_amdgcn_mfma_f32_16x16x32_bf16(ahi[mf], blo, ACC[mf][nf], 0, 0, 0); \
                ACC[mf][nf] = __builtin_amdgcn_mfma_f32_16x16x32_bf16(alo[mf], bhi, ACC[mf][nf], 0, 0, 0); \
                ACC[mf][nf] = __builtin_amdgcn_mfma_f32_16x16x32_bf16(ahi[mf], bhi, ACC[mf][nf], 0, 0, 0); \
            }                                                                     \
        }                                                                         \
    }

// per-row top2 over one 128-col tile; D mapping col=lane&15, row=(lane>>4)*4+reg [m89]
#define TOP2(ACC, JBASE)                                                          \
    _Pragma("unroll")                                                             \
    for (int mf = 0; mf < 2; ++mf)                                                \
    _Pragma("unroll")                                                             \
        for (int reg = 0; reg < 4; ++reg) {                                       \
            int q = mf * 4 + reg;                                                 \
            float v1 = ACC[mf][0][reg];                                           \
            int i1 = (JBASE) + wc * 64 + lr;                                      \
            float v2 = -1e30f;                                                    \
            _Pragma("unroll")                                                     \
            for (int nf = 1; nf < 4; ++nf) {                                      \
                float xv = ACC[mf][nf][reg];                                      \
                int xi = (JBASE) + wc * 64 + nf * 16 + lr;                        \
                if (xv > v1) { v2 = v1; v1 = xv; i1 = xi; }                       \
                else v2 = fmaxf(v2, xv);                                          \
            }                                                                     \
            _Pragma("unroll")                                                     \
            for (int d = 1; d < 16; d <<= 1) {                                    \
                float ov1 = __shfl_xor(v1, d, 64);                                \
                int oi1 = __shfl_xor(i1, d, 64);                                  \
                float ov2 = __shfl_xor(v2, d, 64);                                \
                bool take = (ov1 > v1) || (ov1 == v1 && oi1 < i1);                \
                float bw = take ? v1 : ov1;                                       \
                v2 = fmaxf(fmaxf(v2, ov2), bw);                                   \
                if (take) { v1 = ov1; i1 = oi1; }                                 \
            }                                                                     \
            bool t2 = (v1 > rv1[q]);                                              \
            float bw2 = t2 ? rv1[q] : v1;                                         \
            rv2[q] = fmaxf(fmaxf(rv2[q], v2), bw2);                               \
            if (t2) { rv1[q] = v1; ri1[q] = i1; }                                 \
        }

__global__ void __launch_bounds__(256, 3) k_sim(const float* __restrict__ Ap,
                                                const float* __restrict__ Bp,
                                                float* __restrict__ Pv1, int* __restrict__ Pi1,
                                                float* __restrict__ Pv2) {
    __shared__ __align__(16) char lds[49152];   // Ah 8K | Al 8K | Bh 16K | Bl 16K (swizzled)
    char* Ah = lds;
    char* Al = lds + 8192;
    char* Bh = lds + 16384;
    char* Bl = lds + 32768;
    // T1: XCD-aware bijective swizzle of the 3072-block 1D grid (3072 % 8 == 0).
    // Per XCD: 384 contiguous swz = 24 (b,ch) groups x 16 i-tiles; per-group
    // working set = 1MB A-batch + 256KB B-chunk -> fits one 4MB L2.
    const int flat = blockIdx.x;
    const int swz = (flat & 7) * 384 + (flat >> 3);
    const int bx = swz & 15;                    // i-tile (16)
    const int rest = swz >> 4;
    const int ch = rest % NCH;                  // j-chunk (12)
    const int b = rest / NCH;                   // batch (16)
    const int i0 = bx * 64;
    const int tid = threadIdx.x;
    const int l = tid & 63, wid = tid >> 6;
    const int wr = wid >> 1, wc = wid & 1;      // 2x2 wave grid: 32 i x 64 j per wave per tile
    const int lr = l & 15, lk = l >> 4;
    const float* Abase = Ap + ((size_t)b * NA + i0) * CC;
    const float* Bbase = Bp + (size_t)b * NB * CC;
    const int j0c = ch * 256;

    float rv1[8], rv2[8];
    int ri1[8];
#pragma unroll
    for (int q = 0; q < 8; ++q) { rv1[q] = -1e30f; rv2[q] = -1e30f; ri1[q] = 0; }

    f32x4 acc0[2][4], acc1[2][4];
#pragma unroll
    for (int mf = 0; mf < 2; ++mf)
#pragma unroll
        for (int nf = 0; nf < 4; ++nf) {
            acc0[mf][nf] = (f32x4){0.f, 0.f, 0.f, 0.f};
            acc1[mf][nf] = (f32x4){0.f, 0.f, 0.f, 0.f};
        }

    float4 rA[2][2], rB[4][2];
    LOADTN(Abase, 0, rA, 2)
    LOADTN(Bbase + (size_t)j0c * CC, 0, rB, 4)

    for (int kt = 0; kt < 4; ++kt) {
        __syncthreads();                      // prior tile reads done
        WRITETN(rA, Ah, Al, 2)                // split+write prefetched A,B1
        WRITETN(rB, Bh, Bl, 4)
        __syncthreads();
        LOADTN(Bbase + (size_t)(j0c + 128) * CC, kt, rB, 4)   // issue B2 loads under MFMA0
        MFMA_TILE(acc0)
        __syncthreads();                      // MFMA0 done reading Bh/Bl
        WRITETN(rB, Bh, Bl, 4)
        __syncthreads();
        if (kt < 3) {                         // issue next-kt A,B1 loads under MFMA1
            LOADTN(Abase, kt + 1, rA, 2)
            LOADTN(Bbase + (size_t)j0c * CC, kt + 1, rB, 4)
        }
        MFMA_TILE(acc1)
    }

    TOP2(acc0, j0c)                           // ascending j: tile0 then tile1
    TOP2(acc1, j0c + 128)

    // race-free: each wave writes its own (chunk, wc-half) partial
    if (lr == 0) {
        int pch = ch * 2 + wc;
#pragma unroll
        for (int mf = 0; mf < 2; ++mf)
#pragma unroll
            for (int reg = 0; reg < 4; ++reg) {
                int row = i0 + wr * 32 + mf * 16 + lk * 4 + reg;
                size_t o = ((size_t)b * NPART + pch) * NA + row;
                int q = mf * 4 + reg;
                Pv1[o] = rv1[q]; Pi1[o] = ri1[q]; Pv2[o] = rv2[q];
            }
    }
}

// ---------------- K3b: merge partials -> sel + compact flagged worklist ----------------
__global__ void k_reduce2(const float* __restrict__ Pv1, const int* __restrict__ Pi1,
                          const float* __restrict__ Pv2, int* __restrict__ sel,
                          int* __restrict__ wl, int* __restrict__ count) {
    int idx = blockIdx.x * 256 + threadIdx.x;   // b*NA + a
    int b = idx >> 10;
    int a = idx & 1023;
    float v1 = -1e30f, v2 = -1e30f;
    int i1 = 0x7fffffff;
#pragma unroll
    for (int pc = 0; pc < NPART; ++pc) {
        size_t o = ((size_t)b * NPART + pc) * NA + a;
        float nv1 = Pv1[o];
        int ni1 = Pi1[o];
        bool take = (nv1 > v1) || (nv1 == v1 && ni1 < i1);
        float bw = take ? v1 : nv1;
        v2 = fmaxf(fmaxf(v2, Pv2[o]), bw);
        if (take) { v1 = nv1; i1 = ni1; }
    }
    int g = i1 / 3, r = i1 - 3 * g;
    sel[idx] = 4 * g + r + 1;
    if (v1 - v2 < DELTA) {
        int p = atomicAdd(count, 1);
        wl[p] = idx;
    }
}

// ---------------- K3c: exact fp32 re-argmax for flagged rows (worklist) ----------------
__global__ void __launch_bounds__(512) k_fallback(const float* __restrict__ Ap,
                                                  const float* __restrict__ Bp,
                                                  const int* __restrict__ wl,
                                                  const int* __restrict__ count,
                                                  int* __restrict__ sel) {
    int n = *count;
    __shared__ float arow[CC];
    __shared__ float wv[8];
    __shared__ int wi[8];
    int tid = threadIdx.x;                // 512 threads = 8 waves
    int l = tid & 63, w = tid >> 6;
    int lg = l & 15, grp = l >> 4;
    for (int it = blockIdx.x; it < n; it += gridDim.x) {
        int row = wl[it];
        int b = row >> 10, a = row & 1023;
        __syncthreads();                  // protect arow/wv reuse across iterations
        if (tid < 64) *(float4*)&arow[tid * 4] = *(const float4*)(Ap + ((size_t)b * NA + a) * CC + tid * 4);
        __syncthreads();
        float4 av[4];
#pragma unroll
        for (int q = 0; q < 4; ++q) av[q] = *(const float4*)&arow[q * 64 + lg * 4];
        const float* Bb = Bp + (size_t)b * NB * CC;
        float bv = -1e30f;
        int bi = 0;
        for (int j = w * 4 + grp; j < NB; j += 32) {
            const float* br = Bb + (size_t)j * CC + lg * 4;
            float s = 0.f;
#pragma unroll
            for (int q = 0; q < 4; ++q) {
                float4 bb = *(const float4*)(br + q * 64);
                s = fmaf(av[q].w, bb.w, fmaf(av[q].z, bb.z, fmaf(av[q].y, bb.y, fmaf(av[q].x, bb.x, s))));
            }
#pragma unroll
            for (int d = 1; d < 16; d <<= 1) s += __shfl_xor(s, d, 64);
            if (lg == 0 && s > bv) { bv = s; bi = j; }   // ascending per group-lead
        }
#pragma unroll
        for (int d = 16; d < 64; d <<= 1) {
            float ov = __shfl_xor(bv, d, 64);
            int oi = __shfl_xor(bi, d, 64);
            if (ov > bv || (ov == bv && oi < bi)) { bv = ov; bi = oi; }
        }
        if (l == 0) { wv[w] = bv; wi[w] = bi; }
        __syncthreads();
        if (tid == 0) {
            float vm = wv[0]; int im = wi[0];
#pragma unroll
            for (int q = 1; q < 8; ++q)
                if (wv[q] > vm || (wv[q] == vm && wi[q] < im)) { vm = wv[q]; im = wi[q]; }
            int g = im / 3, r = im - 3 * g;
            sel[row] = 4 * g + r + 1;
        }
    }
}

// ---------------- K4a: fuse; one block per (b,c), x-row staged in LDS ----------------
__global__ void k_fuse(const float* __restrict__ x, const int* __restrict__ sel,
                       const float* __restrict__ fwraw, float* __restrict__ F) {
    __shared__ float row[TT];
    int b = blockIdx.y, c = blockIdx.x;
    int tid = threadIdx.x;
    const float* xr = x + ((size_t)b * CC + c) * TT;
#pragma unroll
    for (int r = 0; r < 4; ++r)
        *(float4*)&row[r * 1024 + tid * 4] = *(const float4*)(xr + r * 1024 + tid * 4);
    float w0 = fminf(fmaxf(fwraw[0], 0.f), 6.f);
    float w1 = fminf(fmaxf(fwraw[1], 0.f), 6.f);
    float s = w0 + w1 + 1e-8f;
    float fw0 = w0 / s, fw1 = w1 / s;
    __syncthreads();
    float4 outv;
    float* op = &outv.x;
#pragma unroll
    for (int u = 0; u < 4; ++u) {
        int p = tid * 4 + u;
        int lin = 4 * p;
        int spa = ((lin & 63) == 0) ? lin + 1 : lin - 1;
        int ssim = sel[b * NA + p];
        float xa = row[lin], xs = row[ssim], xp = row[spa];
        float ms = (xa + xs) * 0.5f;
        float mp = (xa + xp) * 0.5f;
        op[u] = fw0 * ms + fw1 * mp;
    }
    *(float4*)(F + ((size_t)b * CC + c) * NA + tid * 4) = outv;
}

// ---------------- K4b: 1x1 conv via MFMA (bf16 hi/lo 3-pass) + BN + SiLU ----------------
__global__ void __launch_bounds__(256, 3) k_conv(const float* __restrict__ F, const float* __restrict__ W,
                                                 const float* __restrict__ gamma, const float* __restrict__ beta,
                                                 const float* __restrict__ mean, const float* __restrict__ var,
                                                 float* __restrict__ out) {
    __shared__ __align__(16) char lds[49408];   // Wh 8K | Wl 8K | Ff[64][129] fp32 33024B
    char* Wh = lds;
    char* Wl = lds + 8192;
    float* Ff = (float*)(lds + 16384);
    const int b = blockIdx.z;
    const int o0 = blockIdx.y * 64;
    const int p0 = blockIdx.x * 128;
    const int tid = threadIdx.x;
    const int l = tid & 63, wid = tid >> 6;
    const int wr = wid >> 1, wc = wid & 1;      // wave tile: 32 o x 64 p
    const int lr = l & 15, lk = l >> 4;
    const float* Wbase = W + (size_t)o0 * CC;
    const float* Fb = F + (size_t)b * CC * NA;

    f32x4 acc[2][4];
#pragma unroll
    for (int mf = 0; mf < 2; ++mf)
#pragma unroll
        for (int nf = 0; nf < 4; ++nf) acc[mf][nf] = (f32x4){0.f, 0.f, 0.f, 0.f};

    for (int kt = 0; kt < 4; ++kt) {
        __syncthreads();
        // stage W 64o x 64c -> swizzled bf16 hi/lo
#pragma unroll
        for (int rep = 0; rep < 2; ++rep) {
            int lin = rep * 256 + tid;
            int r = lin >> 3, g = lin & 7;
            const float* sp = Wbase + (size_t)r * CC + kt * 64 + g * 8;
            float4 q0 = *(const float4*)sp;
            float4 q1 = *(const float4*)(sp + 4);
            bf16x8 h8, l8;
            split8(q0, q1, h8, l8);
            int off = r * 128 + ((g ^ (r & 7)) << 4);
            *(bf16x8*)(Wh + off) = h8;
            *(bf16x8*)(Wl + off) = l8;
        }
        // stage F 64c x 128p fp32 (c-major, pad 129), coalesced loads
#pragma unroll
        for (int rep = 0; rep < 8; ++rep) {
            int lin = rep * 256 + tid;
            int c = lin >> 5, i4 = lin & 31;
            float4 fv = *(const float4*)(Fb + (size_t)(kt * 64 + c) * NA + p0 + i4 * 4);
            float* dp = Ff + c * 129 + i4 * 4;
            dp[0] = fv.x; dp[1] = fv.y; dp[2] = fv.z; dp[3] = fv.w;
        }
        __syncthreads();
#pragma unroll
        for (int ks = 0; ks < 2; ++ks) {
            bf16x8 whi[2], wlo[2];
#pragma unroll
            for (int mf = 0; mf < 2; ++mf) {
                int ra = wr * 32 + mf * 16 + lr;
                int offa = ra * 128 + (((ks * 4 + lk) ^ (ra & 7)) << 4);
                whi[mf] = *(const bf16x8*)(Wh + offa);
                wlo[mf] = *(const bf16x8*)(Wl + offa);
            }
#pragma unroll
            for (int nf = 0; nf < 4; ++nf) {
                int rb = wc * 64 + nf * 16 + lr;          // p within tile
                const float* cp = Ff + (ks * 4 + lk) * 8 * 129 + rb;
                bf16x8 bhi, blo;
#pragma unroll
                for (int e = 0; e < 8; ++e) {
                    float fv = cp[e * 129];
                    uint u = __float_as_uint(fv);
                    bhi[e] = (short)(u >> 16);
                    float hf = __uint_as_float(u & 0xffff0000u);
                    blo[e] = (short)(__float_as_uint(fv - hf) >> 16);
                }
#pragma unroll
                for (int mf = 0; mf < 2; ++mf) {
                    acc[mf][nf] = __builtin_amdgcn_mfma_f32_16x16x32_bf16(whi[mf], blo, acc[mf][nf], 0, 0, 0);
                    acc[mf][nf] = __builtin_amdgcn_mfma_f32_16x16x32_bf16(wlo[mf], bhi, acc[mf][nf], 0, 0, 0);
                    acc[mf][nf] = __builtin_amdgcn_mfma_f32_16x16x32_bf16(whi[mf], bhi, acc[mf][nf], 0, 0, 0);
                }
            }
        }
    }
    // epilogue: BN + SiLU; D row=o (lk*4+reg within 16), col=p (lr) [m89]
#pragma unroll
    for (int mf = 0; mf < 2; ++mf)
#pragma unroll
        for (int reg = 0; reg < 4; ++reg) {
            int o = o0 + wr * 32 + mf * 16 + lk * 4 + reg;
            float sc = gamma[o] / sqrtf(var[o] + 1e-5f);
            float sh = fmaf(-mean[o], sc, beta[o]);
#pragma unroll
            for (int nf = 0; nf < 4; ++nf) {
                float y = fmaf(acc[mf][nf][reg], sc, sh);
                out[((size_t)b * OC + o) * NA + p0 + wc * 64 + nf * 16 + lr] = y / (1.f + expf(-y));
            }
        }
}

extern "C" void kernel_launch(void* const* d_in, const int* in_sizes, int n_in,
                              void* d_out, int out_size, void* d_ws, size_t ws_size,
                              hipStream_t stream) {
    const float* x      = (const float*)d_in[0];
    const float* conv_w = (const float*)d_in[1];
    const float* gamma  = (const float*)d_in[2];
    const float* beta   = (const float*)d_in[3];
    const float* mean   = (const float*)d_in[4];
    const float* var    = (const float*)d_in[5];
    const float* fw     = (const float*)d_in[6];
    float* out = (float*)d_out;

    float* ws     = (float*)d_ws;
    float* Ap     = ws;                                      // BB*NA*CC f
    float* Bp     = Ap + (size_t)BB * NA * CC;               // BB*NB*CC f
    float* Pv1    = Bp + (size_t)BB * NB * CC;               // BB*NPART*NA f
    float* Pv2    = Pv1 + (size_t)BB * NPART * NA;           // BB*NPART*NA f
    int*   Pi1    = (int*)(Pv2 + (size_t)BB * NPART * NA);   // BB*NPART*NA i
    int*   sel    = Pi1 + (size_t)BB * NPART * NA;           // BB*NA i
    int*   wl     = sel + (size_t)BB * NA;                   // BB*NA i
    int*   count  = wl + (size_t)BB * NA;                    // 1 i
    float* F      = Ap;                                      // reuse Ap region after fallback

    k_pack<<<dim3(TT / 64, BB), 256, 0, stream>>>(x, Ap, Bp, count);
    k_sim<<<16 * NCH * BB, 256, 0, stream>>>(Ap, Bp, Pv1, Pi1, Pv2);
    k_reduce2<<<BB * NA / 256, 256, 0, stream>>>(Pv1, Pi1, Pv2, sel, wl, count);
    k_fallback<<<2048, 512, 0, stream>>>(Ap, Bp, wl, count, sel);
    k_fuse<<<dim3(CC, BB), 256, 0, stream>>>(x, sel, fw, F);
    k_conv<<<dim3(NA / 128, OC / 64, BB), 256, 0, stream>>>(F, conv_w, gamma, beta, mean, var, out);
}